// Round 1
// 1023.352 us; speedup vs baseline: 1.7916x; 1.7916x over previous
//
#include <hip/hip_runtime.h>

typedef __bf16 bf16_t;
typedef bf16_t bf16x8 __attribute__((ext_vector_type(8)));
typedef float floatx4 __attribute__((ext_vector_type(4)));

#define HIDDEN 2048
#define NHEADS 32
#define NKV 8
#define HD 64
#define INTER 8192
#define SEQQ 2048
#define SEQK 2048
#define NBATCH 2
#define NEGBIG (-3.0e38f)

__device__ __forceinline__ floatx4 mfma16(bf16x8 a, bf16x8 b, floatx4 c) {
  return __builtin_amdgcn_mfma_f32_16x16x32_bf16(a, b, c, 0, 0, 0);
}

// pack 8 f32 -> 8 bf16 (as uint4) from two float4 loads
__device__ __forceinline__ uint4 pack8(const float* __restrict__ p) {
  float4 f0 = *(const float4*)p;
  float4 f1 = *(const float4*)(p + 4);
  union { uint4 u; bf16_t e[8]; } r;
  r.e[0] = (bf16_t)f0.x; r.e[1] = (bf16_t)f0.y; r.e[2] = (bf16_t)f0.z; r.e[3] = (bf16_t)f0.w;
  r.e[4] = (bf16_t)f1.x; r.e[5] = (bf16_t)f1.y; r.e[6] = (bf16_t)f1.z; r.e[7] = (bf16_t)f1.w;
  return r.u;
}

// ---------------- f32 -> bf16 bulk convert (grid-stride, 32B read / 16B write per thread-iter)
__global__ __launch_bounds__(256) void cvt_kernel(const float* __restrict__ src,
                                                  bf16_t* __restrict__ dst, int n8) {
  const int stride = gridDim.x * 256;
  for (int i = blockIdx.x * 256 + threadIdx.x; i < n8; i += stride)
    *(uint4*)(dst + (size_t)i * 8) = pack8(src + (size_t)i * 8);
}

// ---------------- RMSNorm: one row (2048 f32) per 256-thread block -> bf16 ----------------
__global__ __launch_bounds__(256) void rmsnorm_kernel(const float* __restrict__ x,
                                                      const float* __restrict__ w,
                                                      bf16_t* __restrict__ y) {
  const int row = blockIdx.x;
  const int tid = threadIdx.x;
  const float* xr = x + (size_t)row * HIDDEN + tid * 8;
  float4 x0 = *(const float4*)xr;
  float4 x1 = *(const float4*)(xr + 4);
  float xf[8] = {x0.x, x0.y, x0.z, x0.w, x1.x, x1.y, x1.z, x1.w};
  float ss = 0.f;
#pragma unroll
  for (int j = 0; j < 8; ++j) ss += xf[j] * xf[j];
#pragma unroll
  for (int off = 32; off >= 1; off >>= 1) ss += __shfl_xor(ss, off);
  __shared__ float red[4];
  if ((tid & 63) == 0) red[tid >> 6] = ss;
  __syncthreads();
  float tot = red[0] + red[1] + red[2] + red[3];
  float rs = 1.0f / sqrtf(tot / (float)HIDDEN + 1e-5f);
  const float* wr = w + tid * 8;
  float4 w0 = *(const float4*)wr;
  float4 w1 = *(const float4*)(wr + 4);
  float wf[8] = {w0.x, w0.y, w0.z, w0.w, w1.x, w1.y, w1.z, w1.w};
  bf16x8 ov;
#pragma unroll
  for (int j = 0; j < 8; ++j) ov[j] = (bf16_t)(xf[j] * rs * wf[j]);
  *(bf16x8*)(y + (size_t)row * HIDDEN + tid * 8) = ov;
}

// ---------------- bf16 staging via global_load_lds, XOR slot-swizzle (rule #21) ------------
// LDS tile layout: [ROWS][64] bf16, row = 128 B = 8 slots of 16 B.
// LDS slot s of row r holds global col-slot (s ^ (r&7)).  Written linearly by
// global_load_lds (lane l -> lds_base + l*16B), with the inverse swizzle applied to the
// per-lane GLOBAL address; ds_read applies the same XOR.  Makes the stride-128B
// ds_read_b128 2-way (free) instead of 16-way conflicted.
template <int ROWS>
__device__ __forceinline__ void stage_tile(bf16_t* lds, const bf16_t* src, int ldK) {
  const int tid = (int)threadIdx.x;
  const int wid = tid >> 6;
  const int row0 = tid >> 3;                          // 0..31 within 32-row chunk
  const int scol = (((tid & 7) ^ (row0 & 7)) * 8);    // swizzled col (elements)
#pragma unroll
  for (int i = 0; i < ROWS / 32; ++i) {
    const bf16_t* g = src + (size_t)(i * 32 + row0) * ldK + scol;
    __builtin_amdgcn_global_load_lds(
        (const __attribute__((address_space(1))) void*)g,
        (__attribute__((address_space(3))) void*)(lds + i * 2048 + wid * 512), 16, 0, 0);
  }
}

__device__ __forceinline__ bf16x8 ldfrag(const bf16_t* lds, int row, int kslot) {
  return *(const bf16x8*)(lds + row * 64 + ((kslot ^ (row & 7)) * 8));
}

// ---------------- bf16 GEMM: C[m,n] = sum_k A[m,k] * W[n,k] (+ f32 residual) --------------
// 128x128 tile, BK=64, 4 waves 2x2, each wave 64x64 (4x4 frags of 16x16x32).
template <int EPI, typename CT>  // EPI 0: C=val; 1: C=val+resid
__global__ __launch_bounds__(256) void gemm_bt16(const bf16_t* __restrict__ A,
                                                 const bf16_t* __restrict__ W,
                                                 const float* __restrict__ resid,
                                                 CT* __restrict__ C, int Kd, int N) {
  const int m0 = blockIdx.y * 128, n0 = blockIdx.x * 128;
  const int tid = threadIdx.x;
  const int wid = tid >> 6, lane = tid & 63, quad = lane >> 4, l15 = lane & 15;
  const int wr = wid >> 1, wc = wid & 1;
  __shared__ __align__(16) bf16_t Asm[128 * 64];
  __shared__ __align__(16) bf16_t Bsm[128 * 64];
  floatx4 acc[4][4];
  floatx4 zero = {0.f, 0.f, 0.f, 0.f};
#pragma unroll
  for (int mi = 0; mi < 4; ++mi)
#pragma unroll
    for (int ni = 0; ni < 4; ++ni) acc[mi][ni] = zero;

  const bf16_t* Ab = A + (size_t)m0 * Kd;
  const bf16_t* Wb = W + (size_t)n0 * Kd;

  for (int kt = 0; kt < Kd; kt += 64) {
    __syncthreads();
    stage_tile<128>(Asm, Ab + kt, Kd);
    stage_tile<128>(Bsm, Wb + kt, Kd);
    __syncthreads();
#pragma unroll
    for (int kk = 0; kk < 2; ++kk) {
      const int ks = kk * 4 + quad;
      bf16x8 af[4], bfr[4];
#pragma unroll
      for (int mi = 0; mi < 4; ++mi) af[mi] = ldfrag(Asm, wr * 64 + mi * 16 + l15, ks);
#pragma unroll
      for (int ni = 0; ni < 4; ++ni) bfr[ni] = ldfrag(Bsm, wc * 64 + ni * 16 + l15, ks);
#pragma unroll
      for (int mi = 0; mi < 4; ++mi)
#pragma unroll
        for (int ni = 0; ni < 4; ++ni) acc[mi][ni] = mfma16(af[mi], bfr[ni], acc[mi][ni]);
    }
  }

#pragma unroll
  for (int mi = 0; mi < 4; ++mi) {
    const int mb = m0 + wr * 64 + mi * 16 + quad * 4;
#pragma unroll
    for (int ni = 0; ni < 4; ++ni) {
      const int n = n0 + wc * 64 + ni * 16 + l15;
      floatx4 v = acc[mi][ni];
#pragma unroll
      for (int r = 0; r < 4; ++r) {
        size_t idx = (size_t)(mb + r) * N + n;
        float val = v[r];
        if (EPI == 1) val += resid[idx];
        C[idx] = (CT)val;
      }
    }
  }
}

// ---------------- Fused gate/up bf16 GEMM with SiLU epilogue -> bf16 ----------------------
// 128(M)x64(N) tile, BK=64, 4 waves 2x2 -> wave tile 64x32; acc 4x2 per output (g,u).
__global__ __launch_bounds__(256) void gateup16(const bf16_t* __restrict__ A,
                                                const bf16_t* __restrict__ Wg,
                                                const bf16_t* __restrict__ Wu,
                                                bf16_t* __restrict__ C, int Kd, int N) {
  const int m0 = blockIdx.y * 128, n0 = blockIdx.x * 64;
  const int tid = threadIdx.x;
  const int wid = tid >> 6, lane = tid & 63, quad = lane >> 4, l15 = lane & 15;
  const int wr = wid >> 1, wc = wid & 1;
  __shared__ __align__(16) bf16_t Asm[128 * 64];
  __shared__ __align__(16) bf16_t Gsm[64 * 64];
  __shared__ __align__(16) bf16_t Usm[64 * 64];
  floatx4 accg[4][2], accu[4][2];
  floatx4 zero = {0.f, 0.f, 0.f, 0.f};
#pragma unroll
  for (int mi = 0; mi < 4; ++mi)
#pragma unroll
    for (int ni = 0; ni < 2; ++ni) { accg[mi][ni] = zero; accu[mi][ni] = zero; }

  const bf16_t* Ab = A + (size_t)m0 * Kd;
  const bf16_t* Gb = Wg + (size_t)n0 * Kd;
  const bf16_t* Ub = Wu + (size_t)n0 * Kd;

  for (int kt = 0; kt < Kd; kt += 64) {
    __syncthreads();
    stage_tile<128>(Asm, Ab + kt, Kd);
    stage_tile<64>(Gsm, Gb + kt, Kd);
    stage_tile<64>(Usm, Ub + kt, Kd);
    __syncthreads();
#pragma unroll
    for (int kk = 0; kk < 2; ++kk) {
      const int ks = kk * 4 + quad;
      bf16x8 af[4];
#pragma unroll
      for (int mi = 0; mi < 4; ++mi) af[mi] = ldfrag(Asm, wr * 64 + mi * 16 + l15, ks);
#pragma unroll
      for (int ni = 0; ni < 2; ++ni) {
        bf16x8 bg = ldfrag(Gsm, wc * 32 + ni * 16 + l15, ks);
        bf16x8 bu = ldfrag(Usm, wc * 32 + ni * 16 + l15, ks);
#pragma unroll
        for (int mi = 0; mi < 4; ++mi) {
          accg[mi][ni] = mfma16(af[mi], bg, accg[mi][ni]);
          accu[mi][ni] = mfma16(af[mi], bu, accu[mi][ni]);
        }
      }
    }
  }

#pragma unroll
  for (int mi = 0; mi < 4; ++mi) {
    const int mb = m0 + wr * 64 + mi * 16 + quad * 4;
#pragma unroll
    for (int ni = 0; ni < 2; ++ni) {
      const int n = n0 + wc * 32 + ni * 16 + l15;
#pragma unroll
      for (int r = 0; r < 4; ++r) {
        float g = accg[mi][ni][r];
        float u = accu[mi][ni][r];
        float act = g / (1.f + __expf(-g)) * u;
        C[(size_t)(mb + r) * N + n] = (bf16_t)act;
      }
    }
  }
}

// ---------------- Flash attention, bf16 K/V input (segment mask + causal, GQA 4:1) --------
__global__ __launch_bounds__(256) void attn16(const bf16_t* __restrict__ qbuf,
                                              const bf16_t* __restrict__ kbuf,
                                              const bf16_t* __restrict__ vbuf,
                                              const int* __restrict__ cuq,
                                              const int* __restrict__ cuk,
                                              bf16_t* __restrict__ obuf) {
  const int qt = blockIdx.x, h = blockIdx.y, b = blockIdx.z;
  const int hk = h >> 2;
  const int tid = threadIdx.x;
  const int wid = tid >> 6, lane = tid & 63, quad = lane >> 4, l15 = lane & 15;
  __shared__ __align__(16) bf16_t Kt[64 * 72];
  __shared__ __align__(16) bf16_t Vt[64 * 72];  // transposed: Vt[d][k]
  __shared__ __align__(16) bf16_t Pt[64 * 72];
  const int cq1 = cuq[1], ck1 = cuk[1];

  const int qrow_a = qt * 64 + wid * 16 + l15;
  const bf16_t* qp = qbuf + ((size_t)(b * SEQQ + qrow_a)) * HIDDEN + h * HD;
  bf16x8 qf0 = *(const bf16x8*)(qp + quad * 8);
  bf16x8 qf1 = *(const bf16x8*)(qp + 32 + quad * 8);

  floatx4 Of[4];
  floatx4 zero = {0.f, 0.f, 0.f, 0.f};
#pragma unroll
  for (int df = 0; df < 4; ++df) Of[df] = zero;
  float m_r[4], l_r[4];
#pragma unroll
  for (int r = 0; r < 4; ++r) { m_r[r] = -1e30f; l_r[r] = 0.f; }
  const int q_row0 = qt * 64 + wid * 16 + quad * 4;
  int seg_q[4];
#pragma unroll
  for (int r = 0; r < 4; ++r) seg_q[r] = (q_row0 + r >= cq1) ? 1 : 0;
  const bool blk_seg1 = (qt * 64 >= cq1);

  const int stag_row = tid >> 3;
  const int stag_c = (tid & 7) * 8;
  const int kt_start = blk_seg1 ? (ck1 >> 6) : 0;

  for (int kt = kt_start; kt <= qt; ++kt) {
    __syncthreads();
#pragma unroll
    for (int i = 0; i < 2; ++i) {
      const int row = stag_row + i * 32;
      const size_t goff = ((size_t)((b * SEQK + kt * 64 + row) * NKV + hk)) * HD + stag_c;
      *(uint4*)&Kt[row * 72 + stag_c] = *(const uint4*)(kbuf + goff);
      bf16x8 vv = *(const bf16x8*)(vbuf + goff);
#pragma unroll
      for (int j = 0; j < 8; ++j) Vt[(stag_c + j) * 72 + row] = vv[j];
    }
    __syncthreads();

    floatx4 sf[4];
#pragma unroll
    for (int nf = 0; nf < 4; ++nf) {
      bf16x8 kf0 = *(const bf16x8*)&Kt[(nf * 16 + l15) * 72 + quad * 8];
      bf16x8 kf1 = *(const bf16x8*)&Kt[(nf * 16 + l15) * 72 + 32 + quad * 8];
      floatx4 a = zero;
      a = mfma16(qf0, kf0, a);
      a = mfma16(qf1, kf1, a);
      sf[nf] = a;
    }

    float tmax[4];
#pragma unroll
    for (int r = 0; r < 4; ++r) tmax[r] = NEGBIG;
#pragma unroll
    for (int nf = 0; nf < 4; ++nf) {
      const int kg = kt * 64 + nf * 16 + l15;
#pragma unroll
      for (int r = 0; r < 4; ++r) {
        const int qg = q_row0 + r;
        const int sk = (kg >= ck1) ? 1 : 0;
        float s = sf[nf][r] * 0.125f;
        bool ok = (kg <= qg) && (sk == seg_q[r]);
        s = ok ? s : NEGBIG;
        sf[nf][r] = s;
        tmax[r] = fmaxf(tmax[r], s);
      }
    }
#pragma unroll
    for (int r = 0; r < 4; ++r) {
#pragma unroll
      for (int off = 1; off <= 8; off <<= 1) tmax[r] = fmaxf(tmax[r], __shfl_xor(tmax[r], off));
    }
    float alpha[4], rsum[4];
#pragma unroll
    for (int r = 0; r < 4; ++r) {
      float mn = fmaxf(m_r[r], tmax[r]);
      alpha[r] = __expf(m_r[r] - mn);
      m_r[r] = mn;
      rsum[r] = 0.f;
    }
#pragma unroll
    for (int nf = 0; nf < 4; ++nf) {
#pragma unroll
      for (int r = 0; r < 4; ++r) {
        float p = __expf(sf[nf][r] - m_r[r]);
        rsum[r] += p;
        Pt[(wid * 16 + quad * 4 + r) * 72 + nf * 16 + l15] = (bf16_t)p;
      }
    }
#pragma unroll
    for (int r = 0; r < 4; ++r) {
#pragma unroll
      for (int off = 1; off <= 8; off <<= 1) rsum[r] += __shfl_xor(rsum[r], off);
      l_r[r] = alpha[r] * l_r[r] + rsum[r];
    }
#pragma unroll
    for (int df = 0; df < 4; ++df) {
#pragma unroll
      for (int r = 0; r < 4; ++r) Of[df][r] *= alpha[r];
    }
#pragma unroll
    for (int kk = 0; kk < 2; ++kk) {
      bf16x8 pf = *(const bf16x8*)&Pt[(wid * 16 + l15) * 72 + kk * 32 + quad * 8];
#pragma unroll
      for (int df = 0; df < 4; ++df) {
        bf16x8 vf = *(const bf16x8*)&Vt[(df * 16 + l15) * 72 + kk * 32 + quad * 8];
        Of[df] = mfma16(pf, vf, Of[df]);
      }
    }
  }

  float inv[4];
#pragma unroll
  for (int r = 0; r < 4; ++r) inv[r] = (l_r[r] > 0.f) ? 1.f / l_r[r] : 0.f;
#pragma unroll
  for (int df = 0; df < 4; ++df) {
#pragma unroll
    for (int r = 0; r < 4; ++r) {
      obuf[((size_t)(b * SEQQ + q_row0 + r)) * HIDDEN + h * HD + df * 16 + l15] =
          (bf16_t)(Of[df][r] * inv[r]);
    }
  }
}

// ================= LEGACY PATH (f32 weights on the fly) — fallback if ws too small ========
template <int EPI, typename CT>
__global__ __launch_bounds__(256) void gemm_bt(const bf16_t* __restrict__ A,
                                               const float* __restrict__ W,
                                               const float* __restrict__ resid,
                                               CT* __restrict__ C,
                                               int Kd, int N) {
  const int m0 = blockIdx.y * 128, n0 = blockIdx.x * 128;
  const int tid = threadIdx.x;
  const int wid = tid >> 6, lane = tid & 63, quad = lane >> 4, l15 = lane & 15;
  const int wr = wid >> 1, wc = wid & 1;
  __shared__ __align__(16) bf16_t Asm[128 * 40];
  __shared__ __align__(16) bf16_t Bsm[128 * 40];
  floatx4 acc[4][4];
  floatx4 zero = {0.f, 0.f, 0.f, 0.f};
#pragma unroll
  for (int mi = 0; mi < 4; ++mi)
#pragma unroll
    for (int ni = 0; ni < 4; ++ni) acc[mi][ni] = zero;

  const int r0 = tid >> 2;
  const int c0 = (tid & 3) * 8;

  for (int kt = 0; kt < Kd; kt += 32) {
    __syncthreads();
    uint4 a0 = *(const uint4*)(A + (size_t)(m0 + r0) * Kd + kt + c0);
    uint4 a1 = *(const uint4*)(A + (size_t)(m0 + r0 + 64) * Kd + kt + c0);
    uint4 b0 = pack8(W + (size_t)(n0 + r0) * Kd + kt + c0);
    uint4 b1 = pack8(W + (size_t)(n0 + r0 + 64) * Kd + kt + c0);
    *(uint4*)&Asm[r0 * 40 + c0] = a0;
    *(uint4*)&Asm[(r0 + 64) * 40 + c0] = a1;
    *(uint4*)&Bsm[r0 * 40 + c0] = b0;
    *(uint4*)&Bsm[(r0 + 64) * 40 + c0] = b1;
    __syncthreads();
    bf16x8 af[4], bfrag[4];
#pragma unroll
    for (int mi = 0; mi < 4; ++mi)
      af[mi] = *(const bf16x8*)&Asm[(wr * 64 + mi * 16 + l15) * 40 + quad * 8];
#pragma unroll
    for (int ni = 0; ni < 4; ++ni)
      bfrag[ni] = *(const bf16x8*)&Bsm[(wc * 64 + ni * 16 + l15) * 40 + quad * 8];
#pragma unroll
    for (int mi = 0; mi < 4; ++mi)
#pragma unroll
      for (int ni = 0; ni < 4; ++ni)
        acc[mi][ni] = mfma16(af[mi], bfrag[ni], acc[mi][ni]);
  }

#pragma unroll
  for (int mi = 0; mi < 4; ++mi) {
    const int mb = m0 + wr * 64 + mi * 16 + quad * 4;
#pragma unroll
    for (int ni = 0; ni < 4; ++ni) {
      const int n = n0 + wc * 64 + ni * 16 + l15;
      floatx4 v = acc[mi][ni];
#pragma unroll
      for (int r = 0; r < 4; ++r) {
        size_t idx = (size_t)(mb + r) * N + n;
        float val = v[r];
        if (EPI == 1) val += resid[idx];
        C[idx] = (CT)val;
      }
    }
  }
}

__global__ __launch_bounds__(256) void gemm_gateup(const bf16_t* __restrict__ A,
                                                   const float* __restrict__ Wg,
                                                   const float* __restrict__ Wu,
                                                   bf16_t* __restrict__ C,
                                                   int Kd, int N) {
  const int m0 = blockIdx.y * 128, n0 = blockIdx.x * 128;
  const int tid = threadIdx.x;
  const int wid = tid >> 6, lane = tid & 63, quad = lane >> 4, l15 = lane & 15;
  const int wr = wid >> 1, wc = wid & 1;
  __shared__ __align__(16) bf16_t Asm[128 * 40];
  __shared__ __align__(16) bf16_t Gsm[128 * 40];
  __shared__ __align__(16) bf16_t Usm[128 * 40];
  floatx4 accg[4][4], accu[4][4];
  floatx4 zero = {0.f, 0.f, 0.f, 0.f};
#pragma unroll
  for (int mi = 0; mi < 4; ++mi)
#pragma unroll
    for (int ni = 0; ni < 4; ++ni) { accg[mi][ni] = zero; accu[mi][ni] = zero; }

  const int r0 = tid >> 2;
  const int c0 = (tid & 3) * 8;

  for (int kt = 0; kt < Kd; kt += 32) {
    __syncthreads();
    uint4 a0 = *(const uint4*)(A + (size_t)(m0 + r0) * Kd + kt + c0);
    uint4 a1 = *(const uint4*)(A + (size_t)(m0 + r0 + 64) * Kd + kt + c0);
    uint4 g0 = pack8(Wg + (size_t)(n0 + r0) * Kd + kt + c0);
    uint4 g1 = pack8(Wg + (size_t)(n0 + r0 + 64) * Kd + kt + c0);
    uint4 u0 = pack8(Wu + (size_t)(n0 + r0) * Kd + kt + c0);
    uint4 u1 = pack8(Wu + (size_t)(n0 + r0 + 64) * Kd + kt + c0);
    *(uint4*)&Asm[r0 * 40 + c0] = a0;
    *(uint4*)&Asm[(r0 + 64) * 40 + c0] = a1;
    *(uint4*)&Gsm[r0 * 40 + c0] = g0;
    *(uint4*)&Gsm[(r0 + 64) * 40 + c0] = g1;
    *(uint4*)&Usm[r0 * 40 + c0] = u0;
    *(uint4*)&Usm[(r0 + 64) * 40 + c0] = u1;
    __syncthreads();
    bf16x8 af[4];
#pragma unroll
    for (int mi = 0; mi < 4; ++mi)
      af[mi] = *(const bf16x8*)&Asm[(wr * 64 + mi * 16 + l15) * 40 + quad * 8];
#pragma unroll
    for (int ni = 0; ni < 4; ++ni) {
      bf16x8 bg = *(const bf16x8*)&Gsm[(wc * 64 + ni * 16 + l15) * 40 + quad * 8];
      bf16x8 bu = *(const bf16x8*)&Usm[(wc * 64 + ni * 16 + l15) * 40 + quad * 8];
#pragma unroll
      for (int mi = 0; mi < 4; ++mi) {
        accg[mi][ni] = mfma16(af[mi], bg, accg[mi][ni]);
        accu[mi][ni] = mfma16(af[mi], bu, accu[mi][ni]);
      }
    }
  }

#pragma unroll
  for (int mi = 0; mi < 4; ++mi) {
    const int mb = m0 + wr * 64 + mi * 16 + quad * 4;
#pragma unroll
    for (int ni = 0; ni < 4; ++ni) {
      const int n = n0 + wc * 64 + ni * 16 + l15;
#pragma unroll
      for (int r = 0; r < 4; ++r) {
        float g = accg[mi][ni][r];
        float u = accu[mi][ni][r];
        float act = g / (1.f + __expf(-g)) * u;
        C[(size_t)(mb + r) * N + n] = (bf16_t)act;
      }
    }
  }
}

__global__ __launch_bounds__(256) void attn_kernel(const bf16_t* __restrict__ qbuf,
                                                   const float* __restrict__ kbuf,
                                                   const float* __restrict__ vbuf,
                                                   const int* __restrict__ cuq,
                                                   const int* __restrict__ cuk,
                                                   bf16_t* __restrict__ obuf) {
  const int qt = blockIdx.x, h = blockIdx.y, b = blockIdx.z;
  const int hk = h >> 2;
  const int tid = threadIdx.x;
  const int wid = tid >> 6, lane = tid & 63, quad = lane >> 4, l15 = lane & 15;
  __shared__ __align__(16) bf16_t Kt[64 * 72];
  __shared__ __align__(16) bf16_t Vt[64 * 72];
  __shared__ __align__(16) bf16_t Pt[64 * 72];
  const int cq1 = cuq[1], ck1 = cuk[1];

  const int qrow_a = qt * 64 + wid * 16 + l15;
  const bf16_t* qp = qbuf + ((size_t)(b * SEQQ + qrow_a)) * HIDDEN + h * HD;
  bf16x8 qf0 = *(const bf16x8*)(qp + quad * 8);
  bf16x8 qf1 = *(const bf16x8*)(qp + 32 + quad * 8);

  floatx4 Of[4];
  floatx4 zero = {0.f, 0.f, 0.f, 0.f};
#pragma unroll
  for (int df = 0; df < 4; ++df) Of[df] = zero;
  float m_r[4], l_r[4];
#pragma unroll
  for (int r = 0; r < 4; ++r) { m_r[r] = -1e30f; l_r[r] = 0.f; }
  const int q_row0 = qt * 64 + wid * 16 + quad * 4;
  int seg_q[4];
#pragma unroll
  for (int r = 0; r < 4; ++r) seg_q[r] = (q_row0 + r >= cq1) ? 1 : 0;
  const bool blk_seg1 = (qt * 64 >= cq1);

  const int stag_row = tid >> 3;
  const int stag_c = (tid & 7) * 8;
  const int kt_start = blk_seg1 ? (ck1 >> 6) : 0;

  for (int kt = kt_start; kt <= qt; ++kt) {
    __syncthreads();
#pragma unroll
    for (int i = 0; i < 2; ++i) {
      const int row = stag_row + i * 32;
      const size_t goff = ((size_t)((b * SEQK + kt * 64 + row) * NKV + hk)) * HD + stag_c;
      uint4 kv = pack8(kbuf + goff);
      *(uint4*)&Kt[row * 72 + stag_c] = kv;
      union { uint4 u; bf16_t e[8]; } vv;
      vv.u = pack8(vbuf + goff);
#pragma unroll
      for (int j = 0; j < 8; ++j) Vt[(stag_c + j) * 72 + row] = vv.e[j];
    }
    __syncthreads();

    floatx4 sf[4];
#pragma unroll
    for (int nf = 0; nf < 4; ++nf) {
      bf16x8 kf0 = *(const bf16x8*)&Kt[(nf * 16 + l15) * 72 + quad * 8];
      bf16x8 kf1 = *(const bf16x8*)&Kt[(nf * 16 + l15) * 72 + 32 + quad * 8];
      floatx4 a = zero;
      a = mfma16(qf0, kf0, a);
      a = mfma16(qf1, kf1, a);
      sf[nf] = a;
    }

    float tmax[4];
#pragma unroll
    for (int r = 0; r < 4; ++r) tmax[r] = NEGBIG;
#pragma unroll
    for (int nf = 0; nf < 4; ++nf) {
      const int kg = kt * 64 + nf * 16 + l15;
#pragma unroll
      for (int r = 0; r < 4; ++r) {
        const int qg = q_row0 + r;
        const int sk = (kg >= ck1) ? 1 : 0;
        float s = sf[nf][r] * 0.125f;
        bool ok = (kg <= qg) && (sk == seg_q[r]);
        s = ok ? s : NEGBIG;
        sf[nf][r] = s;
        tmax[r] = fmaxf(tmax[r], s);
      }
    }
#pragma unroll
    for (int r = 0; r < 4; ++r) {
#pragma unroll
      for (int off = 1; off <= 8; off <<= 1) tmax[r] = fmaxf(tmax[r], __shfl_xor(tmax[r], off));
    }
    float alpha[4], rsum[4];
#pragma unroll
    for (int r = 0; r < 4; ++r) {
      float mn = fmaxf(m_r[r], tmax[r]);
      alpha[r] = __expf(m_r[r] - mn);
      m_r[r] = mn;
      rsum[r] = 0.f;
    }
#pragma unroll
    for (int nf = 0; nf < 4; ++nf) {
#pragma unroll
      for (int r = 0; r < 4; ++r) {
        float p = __expf(sf[nf][r] - m_r[r]);
        rsum[r] += p;
        Pt[(wid * 16 + quad * 4 + r) * 72 + nf * 16 + l15] = (bf16_t)p;
      }
    }
#pragma unroll
    for (int r = 0; r < 4; ++r) {
#pragma unroll
      for (int off = 1; off <= 8; off <<= 1) rsum[r] += __shfl_xor(rsum[r], off);
      l_r[r] = alpha[r] * l_r[r] + rsum[r];
    }
#pragma unroll
    for (int df = 0; df < 4; ++df) {
#pragma unroll
      for (int r = 0; r < 4; ++r) Of[df][r] *= alpha[r];
    }
#pragma unroll
    for (int kk = 0; kk < 2; ++kk) {
      bf16x8 pf = *(const bf16x8*)&Pt[(wid * 16 + l15) * 72 + kk * 32 + quad * 8];
#pragma unroll
      for (int df = 0; df < 4; ++df) {
        bf16x8 vf = *(const bf16x8*)&Vt[(df * 16 + l15) * 72 + kk * 32 + quad * 8];
        Of[df] = mfma16(pf, vf, Of[df]);
      }
    }
  }

  float inv[4];
#pragma unroll
  for (int r = 0; r < 4; ++r) inv[r] = (l_r[r] > 0.f) ? 1.f / l_r[r] : 0.f;
#pragma unroll
  for (int df = 0; df < 4; ++df) {
#pragma unroll
    for (int r = 0; r < 4; ++r) {
      obuf[((size_t)(b * SEQQ + q_row0 + r)) * HIDDEN + h * HD + df * 16 + l15] =
          (bf16_t)(Of[df][r] * inv[r]);
    }
  }
}

static inline int cvt_grid(int n8) {
  int g = (n8 + 255) / 256;
  return g > 2048 ? 2048 : g;
}

extern "C" void kernel_launch(void* const* d_in, const int* in_sizes, int n_in,
                              void* d_out, int out_size, void* d_ws, size_t ws_size,
                              hipStream_t stream) {
  const float* x    = (const float*)d_in[0];   // hidden_states [2,2048,2048] f32
  const float* kst  = (const float*)d_in[1];   // key_states   [2,2048,8,64] f32
  const float* vst  = (const float*)d_in[2];   // value_states [2,2048,8,64] f32
  const float* wln1 = (const float*)d_in[4];
  const float* wln2 = (const float*)d_in[5];
  const float* wq   = (const float*)d_in[6];   // [2048,2048] f32
  const float* wo   = (const float*)d_in[7];   // [2048,2048] f32
  const float* wg   = (const float*)d_in[8];   // [8192,2048] f32
  const float* wu   = (const float*)d_in[9];   // [8192,2048] f32
  const float* wd   = (const float*)d_in[10];  // [2048,8192] f32
  const int* cuq    = (const int*)d_in[11];
  const int* cuk    = (const int*)d_in[12];
  float* out = (float*)d_out;                  // f32; also holds `hidden`

  const size_t MB = 1024ull * 1024ull;
  char* ws = (char*)d_ws;
  // Main path workspace: bufA 16 + bufB (64 full / 32 chunked) + bf16 weights 112 + kv 8 MiB
  const bool full = ws_size >= 200 * MB;
  const bool conv = ws_size >= 168 * MB;

  if (conv) {
    bf16_t* bufA = (bf16_t*)ws;                         // 16 MiB
    bf16_t* bufB = (bf16_t*)(ws + 16 * MB);             // 64 (full) / 32 MiB
    char* p = ws + 16 * MB + (full ? 64 : 32) * MB;
    bf16_t* wq16 = (bf16_t*)p; p += 8 * MB;
    bf16_t* wo16 = (bf16_t*)p; p += 8 * MB;
    bf16_t* wg16 = (bf16_t*)p; p += 32 * MB;
    bf16_t* wu16 = (bf16_t*)p; p += 32 * MB;
    bf16_t* wd16 = (bf16_t*)p; p += 32 * MB;
    bf16_t* k16  = (bf16_t*)p; p += 4 * MB;
    bf16_t* v16  = (bf16_t*)p;

    const int n8_qo = 2048 * 2048 / 8;
    const int n8_gud = 8192 * 2048 / 8;
    const int n8_kv = NBATCH * SEQK * NKV * HD / 8;
    cvt_kernel<<<cvt_grid(n8_qo), 256, 0, stream>>>(wq, wq16, n8_qo);
    cvt_kernel<<<cvt_grid(n8_qo), 256, 0, stream>>>(wo, wo16, n8_qo);
    cvt_kernel<<<cvt_grid(n8_gud), 256, 0, stream>>>(wg, wg16, n8_gud);
    cvt_kernel<<<cvt_grid(n8_gud), 256, 0, stream>>>(wu, wu16, n8_gud);
    cvt_kernel<<<cvt_grid(n8_gud), 256, 0, stream>>>(wd, wd16, n8_gud);
    cvt_kernel<<<cvt_grid(n8_kv), 256, 0, stream>>>(kst, k16, n8_kv);
    cvt_kernel<<<cvt_grid(n8_kv), 256, 0, stream>>>(vst, v16, n8_kv);

    // 1. normed = rmsnorm(x, ln1) -> bf16
    rmsnorm_kernel<<<4096, 256, 0, stream>>>(x, wln1, bufA);
    // 2. q = normed @ wq^T -> bf16
    gemm_bt16<0, bf16_t><<<dim3(16, 32), 256, 0, stream>>>(bufA, wq16, nullptr, bufB, 2048, 2048);
    // 3. attn -> bf16
    attn16<<<dim3(32, 32, 2), 256, 0, stream>>>(bufB, k16, v16, cuq, cuk, bufA);
    // 4. hidden = x + attn @ wo^T (f32, in d_out)
    gemm_bt16<1, float><<<dim3(16, 32), 256, 0, stream>>>(bufA, wo16, x, out, 2048, 2048);
    // 5. normed2 = rmsnorm(hidden, ln2) -> bf16
    rmsnorm_kernel<<<4096, 256, 0, stream>>>(out, wln2, bufA);
    // 6/7. MLP (unchunked if workspace allows)
    const int nch = full ? 1 : 2;
    const int mch = 4096 / nch;
    for (int c = 0; c < nch; ++c) {
      const size_t off = (size_t)c * mch;
      gateup16<<<dim3(128, mch / 128), 256, 0, stream>>>(bufA + off * HIDDEN, wg16, wu16,
                                                         bufB, 2048, 8192);
      gemm_bt16<1, float><<<dim3(16, mch / 128), 256, 0, stream>>>(bufB, wd16, out + off * HIDDEN,
                                                                   out + off * HIDDEN, 8192, 2048);
    }
  } else {
    // Legacy path (48 MiB workspace): on-the-fly f32->bf16 in each GEMM.
    bf16_t* bufA = (bf16_t*)ws;
    bf16_t* bufB = (bf16_t*)(ws + 16 * MB);
    rmsnorm_kernel<<<4096, 256, 0, stream>>>(x, wln1, bufA);
    gemm_bt<0, bf16_t><<<dim3(16, 32), 256, 0, stream>>>(bufA, wq, nullptr, bufB, 2048, 2048);
    attn_kernel<<<dim3(32, 32, 2), 256, 0, stream>>>(bufB, kst, vst, cuq, cuk, bufA);
    gemm_bt<1, float><<<dim3(16, 32), 256, 0, stream>>>(bufA, wo, x, out, 2048, 2048);
    rmsnorm_kernel<<<4096, 256, 0, stream>>>(out, wln2, bufA);
    for (int c = 0; c < 2; ++c) {
      const size_t off = (size_t)c * 2048;
      gemm_gateup<<<dim3(64, 16), 256, 0, stream>>>(bufA + off * HIDDEN, wg, wu, bufB, 2048, 8192);
      gemm_bt<1, float><<<dim3(16, 16), 256, 0, stream>>>(bufB, wd, out + off * HIDDEN,
                                                          out + off * HIDDEN, 8192, 2048);
    }
  }
}